// Round 9
// baseline (877.037 us; speedup 1.0000x reference)
//
#include <hip/hip_runtime.h>
#include <hip/hip_bf16.h>

#define D_IN 256
#define D_OUT 64
#define BN_EPS 1e-5f

#define BINSHIFT 6                 // 64 nodes per bin
#define BINCAP 1536                // mean edges/bin 1024, sigma 32 -> +16 sigma
#define PCHUNK 8192                // edges per k_part block

typedef __attribute__((ext_vector_type(4))) float floatx4;
typedef __attribute__((ext_vector_type(8))) __bf16 bf16x8;
typedef __attribute__((ext_vector_type(4))) unsigned uintx4;

// ---- prep: zero bincur+deg, bn params, W split (MFMA B-fragment order) -----
__global__ __launch_bounds__(256) void k_prep(
        const float* __restrict__ W, __bf16* __restrict__ whi, __bf16* __restrict__ wlo,
        const float* __restrict__ bias, const float* __restrict__ gamma,
        const float* __restrict__ beta, const float* __restrict__ rmean,
        const float* __restrict__ rvar,
        float* __restrict__ bnsc, float* __restrict__ bnsh,
        int* __restrict__ bincur, int* __restrict__ deg, int nbins, int N) {
    int b = blockIdx.x, t = threadIdx.x;
    if (b < 8) {                       // zero bincur (nbins <= 2048)
        int i = b * 256 + t;
        if (i < nbins) bincur[i] = 0;
        return;
    }
    if (b == 8) {                      // bn params
        if (t < D_OUT) {
            float sc = rsqrtf(rvar[t] + BN_EPS) * gamma[t];
            bnsc[t] = sc;
            bnsh[t] = (bias[t] - rmean[t]) * sc + beta[t];
        }
        return;
    }
    if (b < 17) {                      // W split: tid 0..2047
        int tid = (b - 9) * 256 + t;
        int lane = tid & 63, c = (tid >> 6) & 7, tt = tid >> 9;
        int row = tt * 16 + (lane & 15);
        int k0 = c * 32 + (lane >> 4) * 8;
        size_t dst = (size_t)tid * 8;
        #pragma unroll
        for (int j = 0; j < 8; ++j) {
            float w = W[(size_t)row * D_IN + k0 + j];
            __bf16 h = (__bf16)w;
            whi[dst + j] = h;
            wlo[dst + j] = (__bf16)(w - (float)h);
        }
        return;
    }
    // zero deg (grid-stride over remaining blocks)
    int stride = (gridDim.x - 17) * 256;
    for (int i = (b - 17) * 256 + t; i < N; i += stride) deg[i] = 0;
}

// ---- binned partition: packed (src<<6 | tgt&63) + per-node degree ----------
__global__ __launch_bounds__(256) void k_part(
        const int* __restrict__ ei, int* __restrict__ bincur, int* __restrict__ deg,
        unsigned* __restrict__ pairs, int E, int nbins) {
    __shared__ int hist[2048];
    __shared__ int base[2048];
    int t = threadIdx.x;
    int e0 = blockIdx.x * PCHUNK;

    for (int j = t; j < nbins; j += 256) hist[j] = 0;
    __syncthreads();

    int cols[PCHUNK / 256];
    int ranks[PCHUNK / 256];
    #pragma unroll
    for (int i = 0; i < PCHUNK / 256; ++i) {
        int e = e0 + i * 256 + t;
        if (e < E) {
            int c = ei[E + e];
            cols[i] = c;
            ranks[i] = atomicAdd(&hist[c >> BINSHIFT], 1);
            atomicAdd(&deg[c], 1);
        }
    }
    __syncthreads();
    for (int j = t; j < nbins; j += 256) {
        int h = hist[j];
        base[j] = h ? atomicAdd(&bincur[j], h) : 0;
    }
    __syncthreads();
    #pragma unroll
    for (int i = 0; i < PCHUNK / 256; ++i) {
        int e = e0 + i * 256 + t;
        if (e < E) {
            int c = cols[i];
            int bin = c >> BINSHIFT;
            int pos = base[bin] + ranks[i];
            if (pos >= BINCAP) pos = BINCAP - 1;     // never-hit safety
            pairs[(size_t)bin * BINCAP + pos] =
                ((unsigned)ei[e] << BINSHIFT) | (unsigned)(c & 63);
        }
    }
}

// ---- y(bf16) = dinv * (x @ W^T) via split-bf16 MFMA; no LDS ----------------
__global__ __launch_bounds__(256) void k_gemm(
        const float* __restrict__ x, const __bf16* __restrict__ whi,
        const __bf16* __restrict__ wlo, const int* __restrict__ deg,
        __bf16* __restrict__ yb, int n) {
    int wave = threadIdx.x >> 6;
    int lane = threadIdx.x & 63;
    int m0 = blockIdx.x * 64 + wave * 16;
    if (m0 >= n) return;
    int q = lane >> 4, cl = lane & 15;
    int arow = m0 + cl; if (arow >= n) arow = n - 1;   // clamp (tail rows unused)
    const float* ap = x + (size_t)arow * D_IN + q * 8;

    floatx4 acc[4] = {{0.f,0.f,0.f,0.f},{0.f,0.f,0.f,0.f},
                      {0.f,0.f,0.f,0.f},{0.f,0.f,0.f,0.f}};

    #pragma unroll
    for (int c = 0; c < 8; ++c) {
        floatx4 a0 = *(const floatx4*)(ap + c * 32);
        floatx4 a1 = *(const floatx4*)(ap + c * 32 + 4);
        bf16x8 ahi, alo;
        #pragma unroll
        for (int j = 0; j < 4; ++j) {
            __bf16 h0 = (__bf16)a0[j];
            __bf16 h1 = (__bf16)a1[j];
            ahi[j] = h0;     alo[j] = (__bf16)(a0[j] - (float)h0);
            ahi[4 + j] = h1; alo[4 + j] = (__bf16)(a1[j] - (float)h1);
        }
        #pragma unroll
        for (int t = 0; t < 4; ++t) {
            size_t fo = ((size_t)(t * 8 + c) * 64 + lane) * 8;
            bf16x8 bh = *(const bf16x8*)(whi + fo);
            bf16x8 bl = *(const bf16x8*)(wlo + fo);
            acc[t] = __builtin_amdgcn_mfma_f32_16x16x32_bf16(ahi, bh, acc[t], 0, 0, 0);
            acc[t] = __builtin_amdgcn_mfma_f32_16x16x32_bf16(alo, bh, acc[t], 0, 0, 0);
            acc[t] = __builtin_amdgcn_mfma_f32_16x16x32_bf16(ahi, bl, acc[t], 0, 0, 0);
        }
    }

    int nb = m0 + q * 4;
    float dv[4];
    #pragma unroll
    for (int r = 0; r < 4; ++r)
        dv[r] = (nb + r < n) ? rsqrtf((float)(deg[nb + r] + 1)) : 0.f;
    #pragma unroll
    for (int t = 0; t < 4; ++t) {
        #pragma unroll
        for (int r = 0; r < 4; ++r) {
            int node = nb + r;
            if (node < n)
                yb[(size_t)node * D_OUT + t * 16 + cl] = (__bf16)(dv[r] * acc[t][r]);
        }
    }
}

// ---- bin-level aggregate: LDS accumulators, edge-parallel gather -----------
// Block per 64-node bin. 8-lane group per edge (16B/lane over the 128B row).
// acc[64][64] fp32 in LDS (16KB); ds atomic float adds (2 lanes/bank = free).
// Epilogue: self-loop + dinv scale + BN + ReLU, batched over the bin.
__global__ __launch_bounds__(256) void k_aggregate(
        const unsigned* __restrict__ pairs, const int* __restrict__ bincur,
        const int* __restrict__ deg, const unsigned* __restrict__ ybf,
        const float* __restrict__ bnsc, const float* __restrict__ bnsh,
        float* __restrict__ out, int n) {
    __shared__ float acc[64][64];
    int bin = blockIdx.x, t = threadIdx.x;

    float* fa = (float*)acc;
    #pragma unroll
    for (int i = 0; i < 16; ++i) fa[t + i * 256] = 0.f;
    __syncthreads();

    int cnt = bincur[bin]; if (cnt > BINCAP) cnt = BINCAP;
    const unsigned* bp = pairs + (size_t)bin * BINCAP;
    int g = t >> 3, sl = t & 7;

    int p = g;
    for (; p + 32 < cnt; p += 64) {          // 2 edges in flight per group
        unsigned pr0 = bp[p], pr1 = bp[p + 32];
        uintx4 v0 = *(const uintx4*)(ybf + (size_t)(pr0 >> BINSHIFT) * 32 + sl * 4);
        uintx4 v1 = *(const uintx4*)(ybf + (size_t)(pr1 >> BINSHIFT) * 32 + sl * 4);
        int t0 = pr0 & 63, t1 = pr1 & 63;
        #pragma unroll
        for (int k = 0; k < 4; ++k) {
            atomicAdd(&acc[t0][sl * 8 + 2 * k],     __uint_as_float(v0[k] << 16));
            atomicAdd(&acc[t0][sl * 8 + 2 * k + 1], __uint_as_float(v0[k] & 0xffff0000u));
        }
        #pragma unroll
        for (int k = 0; k < 4; ++k) {
            atomicAdd(&acc[t1][sl * 8 + 2 * k],     __uint_as_float(v1[k] << 16));
            atomicAdd(&acc[t1][sl * 8 + 2 * k + 1], __uint_as_float(v1[k] & 0xffff0000u));
        }
    }
    for (; p < cnt; p += 32) {
        unsigned pr = bp[p];
        uintx4 v = *(const uintx4*)(ybf + (size_t)(pr >> BINSHIFT) * 32 + sl * 4);
        int tl = pr & 63;
        #pragma unroll
        for (int k = 0; k < 4; ++k) {
            atomicAdd(&acc[tl][sl * 8 + 2 * k],     __uint_as_float(v[k] << 16));
            atomicAdd(&acc[tl][sl * 8 + 2 * k + 1], __uint_as_float(v[k] & 0xffff0000u));
        }
    }
    __syncthreads();

    // epilogue: thread -> (node-local t>>2, channel block (t&3)*16)
    int nl = t >> 2, ch0 = (t & 3) * 16;
    int node = (bin << BINSHIFT) + nl;
    if (node < n) {
        float dv = rsqrtf((float)(deg[node] + 1));
        const unsigned* yr = ybf + (size_t)node * 32 + (t & 3) * 8;   // self row
        #pragma unroll
        for (int j = 0; j < 4; ++j) {
            unsigned u0 = yr[2 * j], u1 = yr[2 * j + 1];
            float s0 = acc[nl][ch0 + 4 * j + 0] + __uint_as_float(u0 << 16);
            float s1 = acc[nl][ch0 + 4 * j + 1] + __uint_as_float(u0 & 0xffff0000u);
            float s2 = acc[nl][ch0 + 4 * j + 2] + __uint_as_float(u1 << 16);
            float s3 = acc[nl][ch0 + 4 * j + 3] + __uint_as_float(u1 & 0xffff0000u);
            floatx4 bs = *(const floatx4*)(bnsc + ch0 + 4 * j);
            floatx4 bh = *(const floatx4*)(bnsh + ch0 + 4 * j);
            float o0 = fmaf(dv * s0, bs[0], bh[0]);
            float o1 = fmaf(dv * s1, bs[1], bh[1]);
            float o2 = fmaf(dv * s2, bs[2], bh[2]);
            float o3 = fmaf(dv * s3, bs[3], bh[3]);
            floatx4 w = { fmaxf(o0, 0.f), fmaxf(o1, 0.f),
                          fmaxf(o2, 0.f), fmaxf(o3, 0.f) };
            *(floatx4*)(out + (size_t)node * D_OUT + ch0 + 4 * j) = w;
        }
    }
}

static inline char* align_up(char* p, size_t a) {
    return (char*)(((uintptr_t)p + a - 1) & ~(uintptr_t)(a - 1));
}

extern "C" void kernel_launch(void* const* d_in, const int* in_sizes, int n_in,
                              void* d_out, int out_size, void* d_ws, size_t ws_size,
                              hipStream_t stream) {
    const float* x     = (const float*)d_in[0];
    const int*   ei    = (const int*)d_in[1];
    const float* W     = (const float*)d_in[2];
    const float* bias  = (const float*)d_in[3];
    const float* gamma = (const float*)d_in[4];
    const float* beta  = (const float*)d_in[5];
    const float* rmean = (const float*)d_in[6];
    const float* rvar  = (const float*)d_in[7];
    float* out = (float*)d_out;

    int N = in_sizes[0] / D_IN;
    int E = in_sizes[1] / 2;
    int nbins = (N + (1 << BINSHIFT) - 1) >> BINSHIFT;   // 1563 for N=100000

    char* p = (char*)d_ws;
    int*      bincur = (int*)p;         p += 2048 * 4;
    int*      deg    = (int*)p;         p += (size_t)N * 4;       p = align_up(p, 256);
    float*    bnsc   = (float*)p;       p += D_OUT * 4;
    float*    bnsh   = (float*)p;       p += D_OUT * 4;           p = align_up(p, 256);
    __bf16*   whi    = (__bf16*)p;      p += (size_t)D_OUT * D_IN * 2; p = align_up(p, 256);
    __bf16*   wlo    = (__bf16*)p;      p += (size_t)D_OUT * D_IN * 2; p = align_up(p, 256);
    __bf16*   yb     = (__bf16*)p;      p += (size_t)N * D_OUT * 2;    p = align_up(p, 256);
    unsigned* pairs  = (unsigned*)p;    // nbins * BINCAP * 4 bytes (~9.6 MB)

    k_prep<<<115, 256, 0, stream>>>(W, whi, wlo, bias, gamma, beta, rmean, rvar,
                                    bnsc, bnsh, bincur, deg, nbins, N);
    k_part<<<(E + PCHUNK - 1) / PCHUNK, 256, 0, stream>>>(ei, bincur, deg, pairs, E, nbins);
    k_gemm<<<(N + 63) / 64, 256, 0, stream>>>(x, whi, wlo, deg, yb, N);
    k_aggregate<<<nbins, 256, 0, stream>>>(pairs, bincur, deg, (const unsigned*)yb,
                                           bnsc, bnsh, out, N);
}

// Round 10
// 368.698 us; speedup vs baseline: 2.3787x; 2.3787x over previous
//
#include <hip/hip_runtime.h>
#include <hip/hip_bf16.h>

#define D_IN 256
#define D_OUT 64
#define BN_EPS 1e-5f

#define BINSHIFT 8                 // 256 nodes per bin
#define BINCAP 4608                // >= max edges per bin (mean 4092, +8 sigma)
#define PCHUNK 8192                // edges per k_part block

typedef __attribute__((ext_vector_type(4))) float floatx4;
typedef __attribute__((ext_vector_type(8))) __bf16 bf16x8;

// ---- prep: zero bincur + bn params + W split (MFMA B-fragment order) -------
__global__ __launch_bounds__(256) void k_prep(
        const float* __restrict__ W, __bf16* __restrict__ whi, __bf16* __restrict__ wlo,
        const float* __restrict__ bias, const float* __restrict__ gamma,
        const float* __restrict__ beta, const float* __restrict__ rmean,
        const float* __restrict__ rvar,
        float* __restrict__ bnsc, float* __restrict__ bnsh,
        int* __restrict__ bincur, int nbins) {
    int b = blockIdx.x, t = threadIdx.x;
    if (b < 2) {
        int i = b * 256 + t;
        if (i < nbins) bincur[i] = 0;
        if (b == 1 && t < D_OUT) {
            float sc = rsqrtf(rvar[t] + BN_EPS) * gamma[t];
            bnsc[t] = sc;
            bnsh[t] = (bias[t] - rmean[t]) * sc + beta[t];
        }
        return;
    }
    int tid = (b - 2) * 256 + t;   // 0..2047
    int lane = tid & 63, c = (tid >> 6) & 7, tt = tid >> 9;
    int row = tt * 16 + (lane & 15);
    int k0 = c * 32 + (lane >> 4) * 8;
    size_t dst = (size_t)tid * 8;
    #pragma unroll
    for (int j = 0; j < 8; ++j) {
        float w = W[(size_t)row * D_IN + k0 + j];
        __bf16 h = (__bf16)w;
        whi[dst + j] = h;
        wlo[dst + j] = (__bf16)(w - (float)h);
    }
}

// ---- binned partition: packed (src<<8 | tgt&255) into bin segments ---------
__global__ __launch_bounds__(256) void k_part(
        const int* __restrict__ ei, int* __restrict__ bincur,
        unsigned* __restrict__ pairs, int E, int nbins) {
    __shared__ int hist[512];
    __shared__ int base[512];
    int t = threadIdx.x;
    int e0 = blockIdx.x * PCHUNK;

    for (int j = t; j < nbins; j += 256) hist[j] = 0;
    __syncthreads();

    int cols[PCHUNK / 256];
    int ranks[PCHUNK / 256];
    #pragma unroll
    for (int i = 0; i < PCHUNK / 256; ++i) {
        int e = e0 + i * 256 + t;
        if (e < E) {
            int c = ei[E + e];
            cols[i] = c;
            ranks[i] = atomicAdd(&hist[c >> BINSHIFT], 1);
        }
    }
    __syncthreads();
    for (int j = t; j < nbins; j += 256)
        base[j] = atomicAdd(&bincur[j], hist[j]);
    __syncthreads();
    #pragma unroll
    for (int i = 0; i < PCHUNK / 256; ++i) {
        int e = e0 + i * 256 + t;
        if (e < E) {
            int c = cols[i];
            int bin = c >> BINSHIFT;
            int pos = base[bin] + ranks[i];
            if (pos >= BINCAP) pos = BINCAP - 1;     // never-hit safety
            pairs[(size_t)bin * BINCAP + pos] =
                ((unsigned)ei[e] << 8) | (unsigned)(c & 255);
        }
    }
}

// ---- per-bin CSR fill, with the bin-offset scan fused in -------------------
__global__ __launch_bounds__(256) void k_fill3(
        const unsigned* __restrict__ pairs, const int* __restrict__ bincur,
        int* __restrict__ off, float* __restrict__ dinv,
        int* __restrict__ srcs, int n, int nbins) {
    __shared__ int hist[256];
    __shared__ int sc[256];
    __shared__ int curs[256];
    __shared__ int sbase;
    int bin = blockIdx.x, t = threadIdx.x;

    // ---- phase A: redundant per-block scan of bin counts ----
    int i0 = 2 * t, i1 = 2 * t + 1;
    int v0 = (i0 < nbins) ? bincur[i0] : 0;
    int v1 = (i1 < nbins) ? bincur[i1] : 0;
    int s = v0 + v1;
    sc[t] = s;
    hist[t] = 0;                      // init for phase B
    __syncthreads();
    for (int o = 1; o < 256; o <<= 1) {
        int v = (t >= o) ? sc[t - o] : 0;
        __syncthreads();
        sc[t] += v;
        __syncthreads();
    }
    int excl = sc[t] - s;
    if (t == (bin >> 1)) sbase = (bin & 1) ? (excl + v0) : excl;
    if (bin == 0 && t == 255) off[n] = sc[255];
    __syncthreads();
    int binoff_b = sbase;

    // ---- phase B: per-bin node histogram -> off/dinv -> CSR scatter ----
    int cnt = bincur[bin];
    const unsigned* bp = pairs + (size_t)bin * BINCAP;
    for (int p = t; p < cnt; p += 256)
        atomicAdd(&hist[bp[p] & 255u], 1);
    __syncthreads();
    int own = hist[t];
    sc[t] = own;
    __syncthreads();
    for (int o = 1; o < 256; o <<= 1) {
        int v = (t >= o) ? sc[t - o] : 0;
        __syncthreads();
        sc[t] += v;
        __syncthreads();
    }
    int base = binoff_b + sc[t] - own;
    int node = (bin << BINSHIFT) + t;
    curs[t] = base;
    if (node < n) {
        off[node] = base;
        dinv[node] = rsqrtf((float)(own + 1));   // +1 self-loop
    }
    __syncthreads();
    for (int p = t; p < cnt; p += 256) {
        unsigned v = bp[p];
        int pos = atomicAdd(&curs[v & 255u], 1);
        srcs[pos] = (int)(v >> 8);
    }
}

// ---- y = dinv * (x @ W^T), written CHANNEL-SPLIT: ys[q][node][16] bf16 -----
// Quarter q (channels 16q..16q+15) is a contiguous N*32B array (3.2 MB) so a
// single aggregation pass over it fits one XCD's 4 MiB L2.
__global__ __launch_bounds__(256) void k_gemm(
        const float* __restrict__ x, const __bf16* __restrict__ whi,
        const __bf16* __restrict__ wlo, const float* __restrict__ dinv,
        __bf16* __restrict__ ys, int n) {
    int wave = threadIdx.x >> 6;
    int lane = threadIdx.x & 63;
    int m0 = blockIdx.x * 64 + wave * 16;
    if (m0 >= n) return;
    int q = lane >> 4, cl = lane & 15;
    int arow = m0 + cl; if (arow >= n) arow = n - 1;   // clamp (tail rows unused)
    const float* ap = x + (size_t)arow * D_IN + q * 8;

    floatx4 acc[4] = {{0.f,0.f,0.f,0.f},{0.f,0.f,0.f,0.f},
                      {0.f,0.f,0.f,0.f},{0.f,0.f,0.f,0.f}};

    #pragma unroll
    for (int c = 0; c < 8; ++c) {
        floatx4 a0 = *(const floatx4*)(ap + c * 32);
        floatx4 a1 = *(const floatx4*)(ap + c * 32 + 4);
        bf16x8 ahi, alo;
        #pragma unroll
        for (int j = 0; j < 4; ++j) {
            __bf16 h0 = (__bf16)a0[j];
            __bf16 h1 = (__bf16)a1[j];
            ahi[j] = h0;     alo[j] = (__bf16)(a0[j] - (float)h0);
            ahi[4 + j] = h1; alo[4 + j] = (__bf16)(a1[j] - (float)h1);
        }
        #pragma unroll
        for (int t = 0; t < 4; ++t) {
            size_t fo = ((size_t)(t * 8 + c) * 64 + lane) * 8;
            bf16x8 bh = *(const bf16x8*)(whi + fo);
            bf16x8 bl = *(const bf16x8*)(wlo + fo);
            acc[t] = __builtin_amdgcn_mfma_f32_16x16x32_bf16(ahi, bh, acc[t], 0, 0, 0);
            acc[t] = __builtin_amdgcn_mfma_f32_16x16x32_bf16(alo, bh, acc[t], 0, 0, 0);
            acc[t] = __builtin_amdgcn_mfma_f32_16x16x32_bf16(ahi, bl, acc[t], 0, 0, 0);
        }
    }

    int nb = m0 + q * 4;
    float dv[4];
    #pragma unroll
    for (int r = 0; r < 4; ++r) dv[r] = (nb + r < n) ? dinv[nb + r] : 0.f;
    #pragma unroll
    for (int t = 0; t < 4; ++t) {
        #pragma unroll
        for (int r = 0; r < 4; ++r) {
            int node = nb + r;
            if (node < n)   // channel t*16+cl -> quarter t, local channel cl
                ys[((size_t)t * n + node) * 16 + cl] = (__bf16)(dv[r] * acc[t][r]);
        }
    }
}

// ---- CSR gather-aggregate, one channel quarter per launch ------------------
// Wave per node; 4-lane group per edge; lane = 4 channels (uint2 = 8B).
// Gather source yq = ys + q*N*16 is 3.2 MB -> L2-resident per XCD.
__device__ __forceinline__ void acc_row(uint2 v, float& a0, float& a1,
                                        float& a2, float& a3) {
    a0 += __uint_as_float(v.x << 16);
    a1 += __uint_as_float(v.x & 0xffff0000u);
    a2 += __uint_as_float(v.y << 16);
    a3 += __uint_as_float(v.y & 0xffff0000u);
}

__global__ __launch_bounds__(256) void k_agg(
        const int* __restrict__ off, const int* __restrict__ srcs,
        const unsigned* __restrict__ yq, const float* __restrict__ dinv,
        const float* __restrict__ bnsc, const float* __restrict__ bnsh,
        float* __restrict__ out, int n, int q) {
    int node = blockIdx.x * 4 + (threadIdx.x >> 6);
    if (node >= n) return;
    int lane = threadIdx.x & 63;
    int g = lane >> 2, sl = lane & 3;        // edge-group (16/wave), sub-lane
    int s = off[node], e2 = off[node + 1];

    float a0 = 0.f, a1 = 0.f, a2 = 0.f, a3 = 0.f;
    float dv = 0.f;
    floatx4 bs, bh;
    if (g == 0) {                            // self-loop + epilogue params
        dv = dinv[node];
        bs = *(const floatx4*)(bnsc + q * 16 + sl * 4);
        bh = *(const floatx4*)(bnsh + q * 16 + sl * 4);
        uint2 v = *(const uint2*)(yq + (size_t)node * 8 + sl * 2);
        acc_row(v, a0, a1, a2, a3);
    }

    int e = s + g;
    for (; e + 48 < e2; e += 64) {           // 4 rows in flight per group
        int r0 = srcs[e], r1 = srcs[e + 16], r2 = srcs[e + 32], r3 = srcs[e + 48];
        uint2 v0 = *(const uint2*)(yq + (size_t)r0 * 8 + sl * 2);
        uint2 v1 = *(const uint2*)(yq + (size_t)r1 * 8 + sl * 2);
        uint2 v2 = *(const uint2*)(yq + (size_t)r2 * 8 + sl * 2);
        uint2 v3 = *(const uint2*)(yq + (size_t)r3 * 8 + sl * 2);
        acc_row(v0, a0, a1, a2, a3);
        acc_row(v1, a0, a1, a2, a3);
        acc_row(v2, a0, a1, a2, a3);
        acc_row(v3, a0, a1, a2, a3);
    }
    for (; e + 16 < e2; e += 32) {           // 2 rows in flight
        int r0 = srcs[e], r1 = srcs[e + 16];
        uint2 v0 = *(const uint2*)(yq + (size_t)r0 * 8 + sl * 2);
        uint2 v1 = *(const uint2*)(yq + (size_t)r1 * 8 + sl * 2);
        acc_row(v0, a0, a1, a2, a3);
        acc_row(v1, a0, a1, a2, a3);
    }
    for (; e < e2; e += 16) {
        uint2 v = *(const uint2*)(yq + (size_t)srcs[e] * 8 + sl * 2);
        acc_row(v, a0, a1, a2, a3);
    }

    a0 += __shfl_xor(a0, 4);  a1 += __shfl_xor(a1, 4);
    a2 += __shfl_xor(a2, 4);  a3 += __shfl_xor(a3, 4);
    a0 += __shfl_xor(a0, 8);  a1 += __shfl_xor(a1, 8);
    a2 += __shfl_xor(a2, 8);  a3 += __shfl_xor(a3, 8);
    a0 += __shfl_xor(a0, 16); a1 += __shfl_xor(a1, 16);
    a2 += __shfl_xor(a2, 16); a3 += __shfl_xor(a3, 16);
    a0 += __shfl_xor(a0, 32); a1 += __shfl_xor(a1, 32);
    a2 += __shfl_xor(a2, 32); a3 += __shfl_xor(a3, 32);

    if (g == 0) {
        float o0 = fmaf(dv * a0, bs[0], bh[0]);
        float o1 = fmaf(dv * a1, bs[1], bh[1]);
        float o2 = fmaf(dv * a2, bs[2], bh[2]);
        float o3 = fmaf(dv * a3, bs[3], bh[3]);
        floatx4 o = { o0 > 0.f ? o0 : 0.f, o1 > 0.f ? o1 : 0.f,
                      o2 > 0.f ? o2 : 0.f, o3 > 0.f ? o3 : 0.f };
        *(floatx4*)(out + (size_t)node * D_OUT + q * 16 + sl * 4) = o;
    }
}

static inline char* align_up(char* p, size_t a) {
    return (char*)(((uintptr_t)p + a - 1) & ~(uintptr_t)(a - 1));
}

extern "C" void kernel_launch(void* const* d_in, const int* in_sizes, int n_in,
                              void* d_out, int out_size, void* d_ws, size_t ws_size,
                              hipStream_t stream) {
    const float* x     = (const float*)d_in[0];
    const int*   ei    = (const int*)d_in[1];
    const float* W     = (const float*)d_in[2];
    const float* bias  = (const float*)d_in[3];
    const float* gamma = (const float*)d_in[4];
    const float* beta  = (const float*)d_in[5];
    const float* rmean = (const float*)d_in[6];
    const float* rvar  = (const float*)d_in[7];
    float* out = (float*)d_out;

    int N = in_sizes[0] / D_IN;
    int E = in_sizes[1] / 2;
    int nbins = (N + (1 << BINSHIFT) - 1) >> BINSHIFT;   // 391 for N=100000

    char* p = (char*)d_ws;
    int*      bincur = (int*)p;         p += 512 * 4;
    int*      off    = (int*)p;         p += (size_t)(N + 1) * 4; p = align_up(p, 256);
    float*    dinv   = (float*)p;       p += (size_t)N * 4;       p = align_up(p, 256);
    float*    bnsc   = (float*)p;       p += D_OUT * 4;
    float*    bnsh   = (float*)p;       p += D_OUT * 4;           p = align_up(p, 256);
    __bf16*   whi    = (__bf16*)p;      p += (size_t)D_OUT * D_IN * 2; p = align_up(p, 256);
    __bf16*   wlo    = (__bf16*)p;      p += (size_t)D_OUT * D_IN * 2; p = align_up(p, 256);
    __bf16*   ys     = (__bf16*)p;      p += (size_t)N * D_OUT * 2;    p = align_up(p, 256);
    int*      srcs   = (int*)p;         p += (size_t)E * 4;       p = align_up(p, 256);
    unsigned* pairs  = (unsigned*)p;    // nbins * BINCAP * 4 bytes (~7.2 MB)

    k_prep<<<10, 256, 0, stream>>>(W, whi, wlo, bias, gamma, beta, rmean, rvar,
                                   bnsc, bnsh, bincur, nbins);
    k_part<<<(E + PCHUNK - 1) / PCHUNK, 256, 0, stream>>>(ei, bincur, pairs, E, nbins);
    k_fill3<<<nbins, 256, 0, stream>>>(pairs, bincur, off, dinv, srcs, N, nbins);
    k_gemm<<<(N + 63) / 64, 256, 0, stream>>>(x, whi, wlo, dinv, ys, N);
    for (int q = 0; q < 4; ++q) {
        const unsigned* yq = (const unsigned*)(ys + (size_t)q * N * 16);
        k_agg<<<(N + 3) / 4, 256, 0, stream>>>(off, srcs, yq, dinv,
                                               bnsc, bnsh, out, N, q);
    }
}

// Round 11
// 285.444 us; speedup vs baseline: 3.0725x; 1.2917x over previous
//
#include <hip/hip_runtime.h>
#include <hip/hip_bf16.h>

#define D_IN 256
#define D_OUT 64
#define BN_EPS 1e-5f

#define BINSHIFT 8                 // 256 nodes per bin
#define BINCAP 4608                // >= max edges per bin (mean 4092, +8 sigma)
#define PCHUNK 8192                // edges per k_part block

typedef __attribute__((ext_vector_type(4))) float floatx4;
typedef __attribute__((ext_vector_type(8))) __bf16 bf16x8;
typedef __attribute__((ext_vector_type(4))) unsigned uintx4;

// ---- prep: zero bincur + bn params + W split (MFMA B-fragment order) -------
__global__ __launch_bounds__(256) void k_prep(
        const float* __restrict__ W, __bf16* __restrict__ whi, __bf16* __restrict__ wlo,
        const float* __restrict__ bias, const float* __restrict__ gamma,
        const float* __restrict__ beta, const float* __restrict__ rmean,
        const float* __restrict__ rvar,
        float* __restrict__ bnsc, float* __restrict__ bnsh,
        int* __restrict__ bincur, int nbins) {
    int b = blockIdx.x, t = threadIdx.x;
    if (b < 2) {
        int i = b * 256 + t;
        if (i < nbins) bincur[i] = 0;
        if (b == 1 && t < D_OUT) {
            float sc = rsqrtf(rvar[t] + BN_EPS) * gamma[t];
            bnsc[t] = sc;
            bnsh[t] = (bias[t] - rmean[t]) * sc + beta[t];
        }
        return;
    }
    int tid = (b - 2) * 256 + t;   // 0..2047
    int lane = tid & 63, c = (tid >> 6) & 7, tt = tid >> 9;
    int row = tt * 16 + (lane & 15);
    int k0 = c * 32 + (lane >> 4) * 8;
    size_t dst = (size_t)tid * 8;
    #pragma unroll
    for (int j = 0; j < 8; ++j) {
        float w = W[(size_t)row * D_IN + k0 + j];
        __bf16 h = (__bf16)w;
        whi[dst + j] = h;
        wlo[dst + j] = (__bf16)(w - (float)h);
    }
}

// ---- binned partition: packed (src<<8 | tgt&255) into bin segments ---------
__global__ __launch_bounds__(256) void k_part(
        const int* __restrict__ ei, int* __restrict__ bincur,
        unsigned* __restrict__ pairs, int E, int nbins) {
    __shared__ int hist[512];
    __shared__ int base[512];
    int t = threadIdx.x;
    int e0 = blockIdx.x * PCHUNK;

    for (int j = t; j < nbins; j += 256) hist[j] = 0;
    __syncthreads();

    int cols[PCHUNK / 256];
    int ranks[PCHUNK / 256];
    #pragma unroll
    for (int i = 0; i < PCHUNK / 256; ++i) {
        int e = e0 + i * 256 + t;
        if (e < E) {
            int c = ei[E + e];
            cols[i] = c;
            ranks[i] = atomicAdd(&hist[c >> BINSHIFT], 1);
        }
    }
    __syncthreads();
    for (int j = t; j < nbins; j += 256)
        base[j] = atomicAdd(&bincur[j], hist[j]);
    __syncthreads();
    #pragma unroll
    for (int i = 0; i < PCHUNK / 256; ++i) {
        int e = e0 + i * 256 + t;
        if (e < E) {
            int c = cols[i];
            int bin = c >> BINSHIFT;
            int pos = base[bin] + ranks[i];
            if (pos >= BINCAP) pos = BINCAP - 1;     // never-hit safety
            pairs[(size_t)bin * BINCAP + pos] =
                ((unsigned)ei[e] << 8) | (unsigned)(c & 255);
        }
    }
}

// ---- per-bin CSR fill: fused bin-offset scan + SINGLE pass over pairs ------
// Phase A: every block redundantly exclusive-scans bincur[0..nbins) in LDS
//          and keeps its own bin's offset; block 0 writes off[N] = E.
// Phase B: one read of the bin's pairs; (pair, rank) kept in registers
//          (18 unrolled iters x 256 thr = 4608 = BINCAP, static indices);
//          node-scan -> off/dinv; scatter srcs from registers (no re-read,
//          no second LDS-atomic pass).
__global__ __launch_bounds__(256) void k_fill3(
        const unsigned* __restrict__ pairs, const int* __restrict__ bincur,
        int* __restrict__ off, float* __restrict__ dinv,
        int* __restrict__ srcs, int n, int nbins) {
    __shared__ int hist[256];
    __shared__ int sc[256];
    __shared__ int nbase[256];
    __shared__ int sbase;
    int bin = blockIdx.x, t = threadIdx.x;

    // ---- phase A: redundant per-block scan of bin counts ----
    int i0 = 2 * t, i1 = 2 * t + 1;
    int v0 = (i0 < nbins) ? bincur[i0] : 0;
    int v1 = (i1 < nbins) ? bincur[i1] : 0;
    int s = v0 + v1;
    sc[t] = s;
    hist[t] = 0;                      // init for phase B
    __syncthreads();
    for (int o = 1; o < 256; o <<= 1) {
        int v = (t >= o) ? sc[t - o] : 0;
        __syncthreads();
        sc[t] += v;
        __syncthreads();
    }
    int excl = sc[t] - s;
    if (t == (bin >> 1)) sbase = (bin & 1) ? (excl + v0) : excl;
    if (bin == 0 && t == 255) off[n] = sc[255];
    __syncthreads();
    int binoff_b = sbase;

    // ---- phase B: single pass -> ranks in registers ----
    int cnt = bincur[bin]; if (cnt > BINCAP) cnt = BINCAP;   // never-hit safety
    const unsigned* bp = pairs + (size_t)bin * BINCAP;
    unsigned vals[BINCAP / 256];
    int rks[BINCAP / 256];
    #pragma unroll
    for (int i = 0; i < BINCAP / 256; ++i) {
        int p = t + i * 256;
        if (p < cnt) {
            unsigned v = bp[p];
            vals[i] = v;
            rks[i] = atomicAdd(&hist[v & 255u], 1);
        }
    }
    __syncthreads();
    int own = hist[t];
    sc[t] = own;
    __syncthreads();
    for (int o = 1; o < 256; o <<= 1) {
        int v = (t >= o) ? sc[t - o] : 0;
        __syncthreads();
        sc[t] += v;
        __syncthreads();
    }
    int base = binoff_b + sc[t] - own;
    nbase[t] = base;
    int node = (bin << BINSHIFT) + t;
    if (node < n) {
        off[node] = base;
        dinv[node] = rsqrtf((float)(own + 1));   // +1 self-loop
    }
    __syncthreads();
    #pragma unroll
    for (int i = 0; i < BINCAP / 256; ++i) {
        int p = t + i * 256;
        if (p < cnt) {
            unsigned v = vals[i];
            srcs[nbase[v & 255u] + rks[i]] = (int)(v >> 8);
        }
    }
}

// ---- y(bf16) = dinv * (x @ W^T) via split-bf16 MFMA; no LDS ----------------
__global__ __launch_bounds__(256) void k_gemm(
        const float* __restrict__ x, const __bf16* __restrict__ whi,
        const __bf16* __restrict__ wlo, const float* __restrict__ dinv,
        __bf16* __restrict__ yb, int n) {
    int wave = threadIdx.x >> 6;
    int lane = threadIdx.x & 63;
    int m0 = blockIdx.x * 64 + wave * 16;
    if (m0 >= n) return;
    int q = lane >> 4, cl = lane & 15;
    int arow = m0 + cl; if (arow >= n) arow = n - 1;   // clamp (tail rows unused)
    const float* ap = x + (size_t)arow * D_IN + q * 8;

    floatx4 acc[4] = {{0.f,0.f,0.f,0.f},{0.f,0.f,0.f,0.f},
                      {0.f,0.f,0.f,0.f},{0.f,0.f,0.f,0.f}};

    #pragma unroll
    for (int c = 0; c < 8; ++c) {
        floatx4 a0 = *(const floatx4*)(ap + c * 32);
        floatx4 a1 = *(const floatx4*)(ap + c * 32 + 4);
        bf16x8 ahi, alo;
        #pragma unroll
        for (int j = 0; j < 4; ++j) {
            __bf16 h0 = (__bf16)a0[j];
            __bf16 h1 = (__bf16)a1[j];
            ahi[j] = h0;     alo[j] = (__bf16)(a0[j] - (float)h0);
            ahi[4 + j] = h1; alo[4 + j] = (__bf16)(a1[j] - (float)h1);
        }
        #pragma unroll
        for (int t = 0; t < 4; ++t) {
            size_t fo = ((size_t)(t * 8 + c) * 64 + lane) * 8;
            bf16x8 bh = *(const bf16x8*)(whi + fo);
            bf16x8 bl = *(const bf16x8*)(wlo + fo);
            acc[t] = __builtin_amdgcn_mfma_f32_16x16x32_bf16(ahi, bh, acc[t], 0, 0, 0);
            acc[t] = __builtin_amdgcn_mfma_f32_16x16x32_bf16(alo, bh, acc[t], 0, 0, 0);
            acc[t] = __builtin_amdgcn_mfma_f32_16x16x32_bf16(ahi, bl, acc[t], 0, 0, 0);
        }
    }

    int nb = m0 + q * 4;
    float dv[4];
    #pragma unroll
    for (int r = 0; r < 4; ++r) dv[r] = (nb + r < n) ? dinv[nb + r] : 0.f;
    #pragma unroll
    for (int t = 0; t < 4; ++t) {
        #pragma unroll
        for (int r = 0; r < 4; ++r) {
            int node = nb + r;
            if (node < n)
                yb[(size_t)node * D_OUT + t * 16 + cl] = (__bf16)(dv[r] * acc[t][r]);
        }
    }
}

// ---- CSR gather-aggregate: eighth-wave per edge, b128 loads ----------------
__device__ __forceinline__ void acc_row4(uintx4 v, float (&a)[8]) {
    #pragma unroll
    for (int k = 0; k < 4; ++k) {
        a[2 * k]     += __uint_as_float(v[k] << 16);
        a[2 * k + 1] += __uint_as_float(v[k] & 0xffff0000u);
    }
}

__global__ __launch_bounds__(256) void k_aggregate(
        const int* __restrict__ off, const int* __restrict__ srcs,
        const unsigned* __restrict__ ybf, const float* __restrict__ dinv,
        const float* __restrict__ bnsc, const float* __restrict__ bnsh,
        float* __restrict__ out, int n) {
    int node = blockIdx.x * 4 + (threadIdx.x >> 6);
    if (node >= n) return;
    int lane = threadIdx.x & 63;
    int g = lane >> 3, sl = lane & 7;        // edge-group, sub-lane (8 channels)
    int s = off[node], e2 = off[node + 1];

    float a[8] = {0.f, 0.f, 0.f, 0.f, 0.f, 0.f, 0.f, 0.f};
    float dv = 0.f;
    floatx4 bs0, bs1, bh0, bh1;
    if (g == 0) {                            // self-loop + epilogue params
        dv = dinv[node];
        bs0 = *(const floatx4*)(bnsc + sl * 8);
        bs1 = *(const floatx4*)(bnsc + sl * 8 + 4);
        bh0 = *(const floatx4*)(bnsh + sl * 8);
        bh1 = *(const floatx4*)(bnsh + sl * 8 + 4);
        uintx4 v = *(const uintx4*)(ybf + (size_t)node * 32 + sl * 4);
        acc_row4(v, a);
    }

    int e = s + g;
    for (; e + 24 < e2; e += 32) {           // 4 rows in flight per group
        int r0 = srcs[e], r1 = srcs[e + 8], r2 = srcs[e + 16], r3 = srcs[e + 24];
        uintx4 v0 = *(const uintx4*)(ybf + (size_t)r0 * 32 + sl * 4);
        uintx4 v1 = *(const uintx4*)(ybf + (size_t)r1 * 32 + sl * 4);
        uintx4 v2 = *(const uintx4*)(ybf + (size_t)r2 * 32 + sl * 4);
        uintx4 v3 = *(const uintx4*)(ybf + (size_t)r3 * 32 + sl * 4);
        acc_row4(v0, a);
        acc_row4(v1, a);
        acc_row4(v2, a);
        acc_row4(v3, a);
    }
    for (; e + 8 < e2; e += 16) {            // 2 rows in flight
        int r0 = srcs[e], r1 = srcs[e + 8];
        uintx4 v0 = *(const uintx4*)(ybf + (size_t)r0 * 32 + sl * 4);
        uintx4 v1 = *(const uintx4*)(ybf + (size_t)r1 * 32 + sl * 4);
        acc_row4(v0, a);
        acc_row4(v1, a);
    }
    for (; e < e2; e += 8) {
        uintx4 v = *(const uintx4*)(ybf + (size_t)srcs[e] * 32 + sl * 4);
        acc_row4(v, a);
    }

    #pragma unroll
    for (int k = 0; k < 8; ++k) {
        a[k] += __shfl_xor(a[k], 8);
        a[k] += __shfl_xor(a[k], 16);
        a[k] += __shfl_xor(a[k], 32);
    }

    if (g == 0) {
        float o[8];
        #pragma unroll
        for (int k = 0; k < 4; ++k) {
            o[k]     = fmaf(dv * a[k],     bs0[k], bh0[k]);
            o[4 + k] = fmaf(dv * a[4 + k], bs1[k], bh1[k]);
        }
        floatx4 w0 = { fmaxf(o[0], 0.f), fmaxf(o[1], 0.f),
                       fmaxf(o[2], 0.f), fmaxf(o[3], 0.f) };
        floatx4 w1 = { fmaxf(o[4], 0.f), fmaxf(o[5], 0.f),
                       fmaxf(o[6], 0.f), fmaxf(o[7], 0.f) };
        *(floatx4*)(out + (size_t)node * D_OUT + sl * 8) = w0;
        *(floatx4*)(out + (size_t)node * D_OUT + sl * 8 + 4) = w1;
    }
}

static inline char* align_up(char* p, size_t a) {
    return (char*)(((uintptr_t)p + a - 1) & ~(uintptr_t)(a - 1));
}

extern "C" void kernel_launch(void* const* d_in, const int* in_sizes, int n_in,
                              void* d_out, int out_size, void* d_ws, size_t ws_size,
                              hipStream_t stream) {
    const float* x     = (const float*)d_in[0];
    const int*   ei    = (const int*)d_in[1];
    const float* W     = (const float*)d_in[2];
    const float* bias  = (const float*)d_in[3];
    const float* gamma = (const float*)d_in[4];
    const float* beta  = (const float*)d_in[5];
    const float* rmean = (const float*)d_in[6];
    const float* rvar  = (const float*)d_in[7];
    float* out = (float*)d_out;

    int N = in_sizes[0] / D_IN;
    int E = in_sizes[1] / 2;
    int nbins = (N + (1 << BINSHIFT) - 1) >> BINSHIFT;   // 391 for N=100000

    char* p = (char*)d_ws;
    int*      bincur = (int*)p;         p += 512 * 4;
    int*      off    = (int*)p;         p += (size_t)(N + 1) * 4; p = align_up(p, 256);
    float*    dinv   = (float*)p;       p += (size_t)N * 4;       p = align_up(p, 256);
    float*    bnsc   = (float*)p;       p += D_OUT * 4;
    float*    bnsh   = (float*)p;       p += D_OUT * 4;           p = align_up(p, 256);
    __bf16*   whi    = (__bf16*)p;      p += (size_t)D_OUT * D_IN * 2; p = align_up(p, 256);
    __bf16*   wlo    = (__bf16*)p;      p += (size_t)D_OUT * D_IN * 2; p = align_up(p, 256);
    __bf16*   yb     = (__bf16*)p;      p += (size_t)N * D_OUT * 2;    p = align_up(p, 256);
    int*      srcs   = (int*)p;         p += (size_t)E * 4;       p = align_up(p, 256);
    unsigned* pairs  = (unsigned*)p;    // nbins * BINCAP * 4 bytes (~7.2 MB)

    k_prep<<<10, 256, 0, stream>>>(W, whi, wlo, bias, gamma, beta, rmean, rvar,
                                   bnsc, bnsh, bincur, nbins);
    k_part<<<(E + PCHUNK - 1) / PCHUNK, 256, 0, stream>>>(ei, bincur, pairs, E, nbins);
    k_fill3<<<nbins, 256, 0, stream>>>(pairs, bincur, off, dinv, srcs, N, nbins);
    k_gemm<<<(N + 63) / 64, 256, 0, stream>>>(x, whi, wlo, dinv, yb, N);
    k_aggregate<<<(N + 3) / 4, 256, 0, stream>>>(off, srcs, (const unsigned*)yb,
                                                 dinv, bnsc, bnsh, out, N);
}

// Round 12
// 275.284 us; speedup vs baseline: 3.1859x; 1.0369x over previous
//
#include <hip/hip_runtime.h>
#include <hip/hip_bf16.h>

#define D_IN 256
#define D_OUT 64
#define BN_EPS 1e-5f

#define BINSHIFT 8                 // 256 nodes per bin
#define BINCAP 4608                // >= max edges per bin (mean 4092, +8 sigma)
#define PCHUNK 8192                // edges per k_part block

typedef __attribute__((ext_vector_type(4))) float floatx4;
typedef __attribute__((ext_vector_type(8))) __bf16 bf16x8;
typedef __attribute__((ext_vector_type(4))) unsigned uintx4;

// ---- fused prep + binned partition ----------------------------------------
// blocks 0..7 : W split into whi/wlo (MFMA B-fragment order)
// block  8    : BN scale/shift precompute
// blocks 9+   : edge partition chunks (bincur pre-zeroed by hipMemsetAsync)
__global__ __launch_bounds__(256) void k_prepart(
        const float* __restrict__ W, __bf16* __restrict__ whi, __bf16* __restrict__ wlo,
        const float* __restrict__ bias, const float* __restrict__ gamma,
        const float* __restrict__ beta, const float* __restrict__ rmean,
        const float* __restrict__ rvar,
        float* __restrict__ bnsc, float* __restrict__ bnsh,
        const int* __restrict__ ei, int* __restrict__ bincur,
        unsigned* __restrict__ pairs, int E, int nbins) {
    int b = blockIdx.x, t = threadIdx.x;
    if (b < 8) {                       // W split: tid 0..2047
        int tid = b * 256 + t;
        int lane = tid & 63, c = (tid >> 6) & 7, tt = tid >> 9;
        int row = tt * 16 + (lane & 15);
        int k0 = c * 32 + (lane >> 4) * 8;
        size_t dst = (size_t)tid * 8;
        #pragma unroll
        for (int j = 0; j < 8; ++j) {
            float w = W[(size_t)row * D_IN + k0 + j];
            __bf16 h = (__bf16)w;
            whi[dst + j] = h;
            wlo[dst + j] = (__bf16)(w - (float)h);
        }
        return;
    }
    if (b == 8) {                      // BN params
        if (t < D_OUT) {
            float sc = rsqrtf(rvar[t] + BN_EPS) * gamma[t];
            bnsc[t] = sc;
            bnsh[t] = (bias[t] - rmean[t]) * sc + beta[t];
        }
        return;
    }

    // ---- partition role ----
    __shared__ int hist[512];
    __shared__ int base[512];
    int e0 = (b - 9) * PCHUNK;

    for (int j = t; j < nbins; j += 256) hist[j] = 0;
    __syncthreads();

    int cols[PCHUNK / 256];
    int rows[PCHUNK / 256];
    int ranks[PCHUNK / 256];
    #pragma unroll
    for (int i = 0; i < PCHUNK / 256; ++i) {
        int e = e0 + i * 256 + t;
        if (e < E) {
            int c = ei[E + e];
            cols[i] = c;
            rows[i] = ei[e];
            ranks[i] = atomicAdd(&hist[c >> BINSHIFT], 1);
        }
    }
    __syncthreads();
    for (int j = t; j < nbins; j += 256)
        base[j] = atomicAdd(&bincur[j], hist[j]);
    __syncthreads();
    #pragma unroll
    for (int i = 0; i < PCHUNK / 256; ++i) {
        int e = e0 + i * 256 + t;
        if (e < E) {
            int c = cols[i];
            int bin = c >> BINSHIFT;
            int pos = base[bin] + ranks[i];
            if (pos >= BINCAP) pos = BINCAP - 1;     // never-hit safety
            pairs[(size_t)bin * BINCAP + pos] =
                ((unsigned)rows[i] << 8) | (unsigned)(c & 255);
        }
    }
}

// ---- per-bin CSR fill: fused bin-offset scan + SINGLE pass over pairs ------
__global__ __launch_bounds__(256) void k_fill3(
        const unsigned* __restrict__ pairs, const int* __restrict__ bincur,
        int* __restrict__ off, float* __restrict__ dinv,
        int* __restrict__ srcs, int n, int nbins) {
    __shared__ int hist[256];
    __shared__ int sc[256];
    __shared__ int nbase[256];
    __shared__ int sbase;
    int bin = blockIdx.x, t = threadIdx.x;

    // ---- phase A: redundant per-block scan of bin counts ----
    int i0 = 2 * t, i1 = 2 * t + 1;
    int v0 = (i0 < nbins) ? bincur[i0] : 0;
    int v1 = (i1 < nbins) ? bincur[i1] : 0;
    int s = v0 + v1;
    sc[t] = s;
    hist[t] = 0;                      // init for phase B
    __syncthreads();
    for (int o = 1; o < 256; o <<= 1) {
        int v = (t >= o) ? sc[t - o] : 0;
        __syncthreads();
        sc[t] += v;
        __syncthreads();
    }
    int excl = sc[t] - s;
    if (t == (bin >> 1)) sbase = (bin & 1) ? (excl + v0) : excl;
    if (bin == 0 && t == 255) off[n] = sc[255];
    __syncthreads();
    int binoff_b = sbase;

    // ---- phase B: single pass -> ranks in registers ----
    int cnt = bincur[bin]; if (cnt > BINCAP) cnt = BINCAP;   // never-hit safety
    const unsigned* bp = pairs + (size_t)bin * BINCAP;
    unsigned vals[BINCAP / 256];
    int rks[BINCAP / 256];
    #pragma unroll
    for (int i = 0; i < BINCAP / 256; ++i) {
        int p = t + i * 256;
        if (p < cnt) {
            unsigned v = bp[p];
            vals[i] = v;
            rks[i] = atomicAdd(&hist[v & 255u], 1);
        }
    }
    __syncthreads();
    int own = hist[t];
    sc[t] = own;
    __syncthreads();
    for (int o = 1; o < 256; o <<= 1) {
        int v = (t >= o) ? sc[t - o] : 0;
        __syncthreads();
        sc[t] += v;
        __syncthreads();
    }
    int base = binoff_b + sc[t] - own;
    nbase[t] = base;
    int node = (bin << BINSHIFT) + t;
    if (node < n) {
        off[node] = base;
        dinv[node] = rsqrtf((float)(own + 1));   // +1 self-loop
    }
    __syncthreads();
    #pragma unroll
    for (int i = 0; i < BINCAP / 256; ++i) {
        int p = t + i * 256;
        if (p < cnt) {
            unsigned v = vals[i];
            srcs[nbase[v & 255u] + rks[i]] = (int)(v >> 8);
        }
    }
}

// ---- y(bf16) = dinv * (x @ W^T) via split-bf16 MFMA; no LDS ----------------
__global__ __launch_bounds__(256) void k_gemm(
        const float* __restrict__ x, const __bf16* __restrict__ whi,
        const __bf16* __restrict__ wlo, const float* __restrict__ dinv,
        __bf16* __restrict__ yb, int n) {
    int wave = threadIdx.x >> 6;
    int lane = threadIdx.x & 63;
    int m0 = blockIdx.x * 64 + wave * 16;
    if (m0 >= n) return;
    int q = lane >> 4, cl = lane & 15;
    int arow = m0 + cl; if (arow >= n) arow = n - 1;   // clamp (tail rows unused)
    const float* ap = x + (size_t)arow * D_IN + q * 8;

    floatx4 acc[4] = {{0.f,0.f,0.f,0.f},{0.f,0.f,0.f,0.f},
                      {0.f,0.f,0.f,0.f},{0.f,0.f,0.f,0.f}};

    #pragma unroll
    for (int c = 0; c < 8; ++c) {
        floatx4 a0 = *(const floatx4*)(ap + c * 32);
        floatx4 a1 = *(const floatx4*)(ap + c * 32 + 4);
        bf16x8 ahi, alo;
        #pragma unroll
        for (int j = 0; j < 4; ++j) {
            __bf16 h0 = (__bf16)a0[j];
            __bf16 h1 = (__bf16)a1[j];
            ahi[j] = h0;     alo[j] = (__bf16)(a0[j] - (float)h0);
            ahi[4 + j] = h1; alo[4 + j] = (__bf16)(a1[j] - (float)h1);
        }
        #pragma unroll
        for (int t = 0; t < 4; ++t) {
            size_t fo = ((size_t)(t * 8 + c) * 64 + lane) * 8;
            bf16x8 bh = *(const bf16x8*)(whi + fo);
            bf16x8 bl = *(const bf16x8*)(wlo + fo);
            acc[t] = __builtin_amdgcn_mfma_f32_16x16x32_bf16(ahi, bh, acc[t], 0, 0, 0);
            acc[t] = __builtin_amdgcn_mfma_f32_16x16x32_bf16(alo, bh, acc[t], 0, 0, 0);
            acc[t] = __builtin_amdgcn_mfma_f32_16x16x32_bf16(ahi, bl, acc[t], 0, 0, 0);
        }
    }

    int nb = m0 + q * 4;
    float dv[4];
    #pragma unroll
    for (int r = 0; r < 4; ++r) dv[r] = (nb + r < n) ? dinv[nb + r] : 0.f;
    #pragma unroll
    for (int t = 0; t < 4; ++t) {
        #pragma unroll
        for (int r = 0; r < 4; ++r) {
            int node = nb + r;
            if (node < n)
                yb[(size_t)node * D_OUT + t * 16 + cl] = (__bf16)(dv[r] * acc[t][r]);
        }
    }
}

// ---- CSR gather-aggregate: eighth-wave per edge, b128 loads ----------------
__device__ __forceinline__ void acc_row4(uintx4 v, float (&a)[8]) {
    #pragma unroll
    for (int k = 0; k < 4; ++k) {
        a[2 * k]     += __uint_as_float(v[k] << 16);
        a[2 * k + 1] += __uint_as_float(v[k] & 0xffff0000u);
    }
}

__global__ __launch_bounds__(256) void k_aggregate(
        const int* __restrict__ off, const int* __restrict__ srcs,
        const unsigned* __restrict__ ybf, const float* __restrict__ dinv,
        const float* __restrict__ bnsc, const float* __restrict__ bnsh,
        float* __restrict__ out, int n) {
    int node = blockIdx.x * 4 + (threadIdx.x >> 6);
    if (node >= n) return;
    int lane = threadIdx.x & 63;
    int g = lane >> 3, sl = lane & 7;        // edge-group, sub-lane (8 channels)
    int s = off[node], e2 = off[node + 1];

    float a[8] = {0.f, 0.f, 0.f, 0.f, 0.f, 0.f, 0.f, 0.f};
    float dv = 0.f;
    floatx4 bs0, bs1, bh0, bh1;
    if (g == 0) {                            // self-loop + epilogue params
        dv = dinv[node];
        bs0 = *(const floatx4*)(bnsc + sl * 8);
        bs1 = *(const floatx4*)(bnsc + sl * 8 + 4);
        bh0 = *(const floatx4*)(bnsh + sl * 8);
        bh1 = *(const floatx4*)(bnsh + sl * 8 + 4);
        uintx4 v = *(const uintx4*)(ybf + (size_t)node * 32 + sl * 4);
        acc_row4(v, a);
    }

    int e = s + g;
    for (; e + 24 < e2; e += 32) {           // 4 rows in flight per group
        int r0 = srcs[e], r1 = srcs[e + 8], r2 = srcs[e + 16], r3 = srcs[e + 24];
        uintx4 v0 = *(const uintx4*)(ybf + (size_t)r0 * 32 + sl * 4);
        uintx4 v1 = *(const uintx4*)(ybf + (size_t)r1 * 32 + sl * 4);
        uintx4 v2 = *(const uintx4*)(ybf + (size_t)r2 * 32 + sl * 4);
        uintx4 v3 = *(const uintx4*)(ybf + (size_t)r3 * 32 + sl * 4);
        acc_row4(v0, a);
        acc_row4(v1, a);
        acc_row4(v2, a);
        acc_row4(v3, a);
    }
    for (; e + 8 < e2; e += 16) {            // 2 rows in flight
        int r0 = srcs[e], r1 = srcs[e + 8];
        uintx4 v0 = *(const uintx4*)(ybf + (size_t)r0 * 32 + sl * 4);
        uintx4 v1 = *(const uintx4*)(ybf + (size_t)r1 * 32 + sl * 4);
        acc_row4(v0, a);
        acc_row4(v1, a);
    }
    for (; e < e2; e += 8) {
        uintx4 v = *(const uintx4*)(ybf + (size_t)srcs[e] * 32 + sl * 4);
        acc_row4(v, a);
    }

    #pragma unroll
    for (int k = 0; k < 8; ++k) {
        a[k] += __shfl_xor(a[k], 8);
        a[k] += __shfl_xor(a[k], 16);
        a[k] += __shfl_xor(a[k], 32);
    }

    if (g == 0) {
        float o[8];
        #pragma unroll
        for (int k = 0; k < 4; ++k) {
            o[k]     = fmaf(dv * a[k],     bs0[k], bh0[k]);
            o[4 + k] = fmaf(dv * a[4 + k], bs1[k], bh1[k]);
        }
        floatx4 w0 = { fmaxf(o[0], 0.f), fmaxf(o[1], 0.f),
                       fmaxf(o[2], 0.f), fmaxf(o[3], 0.f) };
        floatx4 w1 = { fmaxf(o[4], 0.f), fmaxf(o[5], 0.f),
                       fmaxf(o[6], 0.f), fmaxf(o[7], 0.f) };
        *(floatx4*)(out + (size_t)node * D_OUT + sl * 8) = w0;
        *(floatx4*)(out + (size_t)node * D_OUT + sl * 8 + 4) = w1;
    }
}

static inline char* align_up(char* p, size_t a) {
    return (char*)(((uintptr_t)p + a - 1) & ~(uintptr_t)(a - 1));
}

extern "C" void kernel_launch(void* const* d_in, const int* in_sizes, int n_in,
                              void* d_out, int out_size, void* d_ws, size_t ws_size,
                              hipStream_t stream) {
    const float* x     = (const float*)d_in[0];
    const int*   ei    = (const int*)d_in[1];
    const float* W     = (const float*)d_in[2];
    const float* bias  = (const float*)d_in[3];
    const float* gamma = (const float*)d_in[4];
    const float* beta  = (const float*)d_in[5];
    const float* rmean = (const float*)d_in[6];
    const float* rvar  = (const float*)d_in[7];
    float* out = (float*)d_out;

    int N = in_sizes[0] / D_IN;
    int E = in_sizes[1] / 2;
    int nbins = (N + (1 << BINSHIFT) - 1) >> BINSHIFT;   // 391 for N=100000
    int nchunks = (E + PCHUNK - 1) / PCHUNK;             // 196 for E=1.6M

    char* p = (char*)d_ws;
    int*      bincur = (int*)p;         p += 512 * 4;
    int*      off    = (int*)p;         p += (size_t)(N + 1) * 4; p = align_up(p, 256);
    float*    dinv   = (float*)p;       p += (size_t)N * 4;       p = align_up(p, 256);
    float*    bnsc   = (float*)p;       p += D_OUT * 4;
    float*    bnsh   = (float*)p;       p += D_OUT * 4;           p = align_up(p, 256);
    __bf16*   whi    = (__bf16*)p;      p += (size_t)D_OUT * D_IN * 2; p = align_up(p, 256);
    __bf16*   wlo    = (__bf16*)p;      p += (size_t)D_OUT * D_IN * 2; p = align_up(p, 256);
    __bf16*   yb     = (__bf16*)p;      p += (size_t)N * D_OUT * 2;    p = align_up(p, 256);
    int*      srcs   = (int*)p;         p += (size_t)E * 4;       p = align_up(p, 256);
    unsigned* pairs  = (unsigned*)p;    // nbins * BINCAP * 4 bytes (~7.2 MB)

    hipMemsetAsync(bincur, 0, 512 * 4, stream);
    k_prepart<<<9 + nchunks, 256, 0, stream>>>(W, whi, wlo, bias, gamma, beta,
                                               rmean, rvar, bnsc, bnsh,
                                               ei, bincur, pairs, E, nbins);
    k_fill3<<<nbins, 256, 0, stream>>>(pairs, bincur, off, dinv, srcs, N, nbins);
    k_gemm<<<(N + 63) / 64, 256, 0, stream>>>(x, whi, wlo, dinv, yb, N);
    k_aggregate<<<(N + 3) / 4, 256, 0, stream>>>(off, srcs, (const unsigned*)yb,
                                                 dinv, bnsc, bnsh, out, N);
}